// Round 4
// baseline (1413.055 us; speedup 1.0000x reference)
//
#include <hip/hip_runtime.h>

#define SEQ   2048
#define BATCH 256
#define INDIM 64
#define HID   128

struct F2 { float x, y; };

// Permuted value via DPP. CTRL: 0xB1 quad_perm xor1, 0x4E quad_perm xor2,
// 0x124 row_ror:4, 0x128 row_ror:8.
template <int CTRL>
__device__ __forceinline__ float dpp_get(float v) {
    int t = __builtin_amdgcn_update_dpp(0, __builtin_bit_cast(int, v),
                                        CTRL, 0xF, 0xF, true);
    return __builtin_bit_cast(float, t);
}

// Packed fp32 math (VOP3P): 2 FMAs/lane/inst.
#define PK_MUL(d, a, b) asm("v_pk_mul_f32 %0, %1, %2"     : "=v"(d) : "v"(a), "v"(b))
#define PK_FMA(d, a, b) asm("v_pk_fma_f32 %0, %1, %2, %0" : "+v"(d) : "v"(a), "v"(b))

// tanh(d + bias) with bias pre-folded: m = d*K + bias*K, K = -2/ln2;
// e = 2^m = e^{-2(d+bias)}; tanh = (1-e)/(1+e).
#define TANH_K (-2.885390081777927f)
__device__ __forceinline__ float tanh_pre(float d, float bias_k) {
    float m = __builtin_fmaf(d, TANH_K, bias_k);
    float e = __builtin_amdgcn_exp2f(m);
    return (1.0f - e) * __builtin_amdgcn_rcpf(1.0f + e);
}

// R14: PHASE-SHIFTED dual chain. Two batch chains per block, R13's 4-wave
// 32-outputs/wave shell. Each iteration = 2 ticks (2 barriers); in tick1
// chain B's serial tail (reduce+tanh+write) runs under chain A's ds_read
// latency + FMA block; tick2 swaps roles. The shared s_barrier ENFORCES the
// complementary phasing (R11 failed with same-phase lockstep; R12 failed
// with inst-interleave + AGPR parking). waves_per_eu(1,1) keeps the 512-VGPR
// cap -> no parking (R13-proven; ~210 live here).
__global__ __launch_bounds__(256)
__attribute__((amdgpu_waves_per_eu(1, 1)))
void rnn_fused(
    const float* __restrict__ x,    // (S,B,IN)
    const float* __restrict__ Wx,   // (H,IN)
    const float* __restrict__ bx,   // (H)
    const float* __restrict__ Wh,   // (H,H)
    const float* __restrict__ bh,   // (H)
    float* __restrict__ out)        // (S,B,H) then (1,B,H)
{
    const int b0  = blockIdx.x * 2;  // chains b0 (A), b0+1 (B)
    const int tid = threadIdx.x;     // 0..255 (4 waves, 1/SIMD)
    const int l   = tid & 63;
    const int w   = tid >> 6;        // 0..3
    const int s   = l & 15;          // k-slice: h[4s..4s+3], h[64+4s..+3], x[4s..+3]
    const int j0  = w * 32 + (l >> 4) * 8;   // group base: outputs j0..j0+7

    __shared__ __align__(16) float hbuf[2][2][HID];   // [chain][bank][h]

    // ---- weights as packed float-pairs, SLOT-PERMUTED (R13 8-slot scheme):
    // slot o holds output j0 + (o&4) + ((o&3) ^ (l&3)) -> two cndmask-free
    // butterflies per lane. Shared by both chains (weights are chain-invariant).
    const double* WhD = (const double*)Wh;   // 64 doubles per row
    const double* WxD = (const double*)Wx;   // 32 doubles per row
    double wA[8], wB[8], wC[8], wD[8], wX[8], wY[8];
#pragma unroll
    for (int o = 0; o < 8; ++o) {
        const int row = j0 + (o & 4) + ((o & 3) ^ (l & 3));
        const int r   = row * 64 + 2 * s;
        wA[o] = WhD[r];      wB[o] = WhD[r + 1];
        wC[o] = WhD[r + 32]; wD[o] = WhD[r + 33];
        const int rx  = row * 32 + 2 * s;
        wX[o] = WxD[rx];     wY[o] = WxD[rx + 1];
    }
    const int jj  = j0 + (l & 3);        // bank-0 output; bank-1 is jj+4
    float bias_k  = (bx[jj]     + bh[jj])     * TANH_K;
    float bias_k2 = (bx[jj + 4] + bh[jj + 4]) * TANH_K;

    ((float*)hbuf)[tid]       = 0.0f;    // zero all 512 floats (both chains)
    ((float*)hbuf)[tid + 256] = 0.0f;
    __syncthreads();

    // x: per-thread double2 (=float4) slice per chain; 3-deep rotation
    // (cx=current, nx=next, fx=in-flight for i+2) -> vmcnt waits land ~2
    // iterations (~1200cy) after issue, covering cold-HBM latency.
    const double2* xb2a = (const double2*)(x + (size_t)b0 * INDIM + 4 * s);
    const double2* xb2b = (const double2*)(x + (size_t)(b0 + 1) * INDIM + 4 * s);
    const size_t   S2   = (size_t)BATCH * INDIM / 4;   // double2 per timestep

    double2 cxA = xb2a[0],  cxB = xb2b[0];
    double2 nxA = xb2a[S2], nxB = xb2b[S2];
    double2 fxA, fxB;

    float* outpA = out + (size_t)b0 * HID + jj;        // A step-i store (tick2)
    float* outpB = out + (size_t)(b0 + 1) * HID + jj;  // B step-(i-1) store (tick1)
    const bool wr = (s < 4);                   // 16 lanes/wave write
    float hvA1 = 0.0f, hvA2 = 0.0f, hvB1 = 0.0f, hvB2 = 0.0f;
    double accA[8], accB[8];

#define PIN_WEIGHTS()                                                         \
    asm volatile("" : "+v"(wA[0]), "+v"(wA[1]), "+v"(wA[2]), "+v"(wA[3]),      \
                      "+v"(wA[4]), "+v"(wA[5]), "+v"(wA[6]), "+v"(wA[7]));     \
    asm volatile("" : "+v"(wB[0]), "+v"(wB[1]), "+v"(wB[2]), "+v"(wB[3]),      \
                      "+v"(wB[4]), "+v"(wB[5]), "+v"(wB[6]), "+v"(wB[7]));     \
    asm volatile("" : "+v"(wC[0]), "+v"(wC[1]), "+v"(wC[2]), "+v"(wC[3]),      \
                      "+v"(wC[4]), "+v"(wC[5]), "+v"(wC[6]), "+v"(wC[7]));     \
    asm volatile("" : "+v"(wD[0]), "+v"(wD[1]), "+v"(wD[2]), "+v"(wD[3]),      \
                      "+v"(wD[4]), "+v"(wD[5]), "+v"(wD[6]), "+v"(wD[7]));     \
    asm volatile("" : "+v"(wX[0]), "+v"(wX[1]), "+v"(wX[2]), "+v"(wX[3]),      \
                      "+v"(wX[4]), "+v"(wX[5]), "+v"(wX[6]), "+v"(wX[7]));     \
    asm volatile("" : "+v"(wY[0]), "+v"(wY[1]), "+v"(wY[2]), "+v"(wY[3]),      \
                      "+v"(wY[4]), "+v"(wY[5]), "+v"(wY[6]), "+v"(wY[7]));     \
    asm volatile("" : "+v"(bias_k), "+v"(bias_k2));

#define XLOAD(I)                                                              \
    { int tp = (I) + 2; if (tp > SEQ - 1) tp = SEQ - 1;                        \
      fxA = xb2a[(size_t)tp * S2]; fxB = xb2b[(size_t)tp * S2]; }

#define XROT() { cxA = nxA; nxA = fxA; cxB = nxB; nxB = fxB; }

#define FMA8(ACC, XV, H0V, H1V)                                               \
    _Pragma("unroll") for (int o = 0; o < 8; ++o) PK_MUL(ACC[o], (XV).x, wX[o]); \
    _Pragma("unroll") for (int o = 0; o < 8; ++o) PK_FMA(ACC[o], (XV).y, wY[o]); \
    _Pragma("unroll") for (int o = 0; o < 8; ++o) PK_FMA(ACC[o], (H0V).x, wA[o]); \
    _Pragma("unroll") for (int o = 0; o < 8; ++o) PK_FMA(ACC[o], (H0V).y, wB[o]); \
    _Pragma("unroll") for (int o = 0; o < 8; ++o) PK_FMA(ACC[o], (H1V).x, wC[o]); \
    _Pragma("unroll") for (int o = 0; o < 8; ++o) PK_FMA(ACC[o], (H1V).y, wD[o]);

#define REDUCE8(ACC, HV1, HV2)                                                \
    {                                                                         \
        float a0, a1, a2, a3, a4, a5, a6, a7;                                 \
        { F2 u = __builtin_bit_cast(F2, ACC[0]); a0 = u.x + u.y; }            \
        { F2 u = __builtin_bit_cast(F2, ACC[1]); a1 = u.x + u.y; }            \
        { F2 u = __builtin_bit_cast(F2, ACC[2]); a2 = u.x + u.y; }            \
        { F2 u = __builtin_bit_cast(F2, ACC[3]); a3 = u.x + u.y; }            \
        { F2 u = __builtin_bit_cast(F2, ACC[4]); a4 = u.x + u.y; }            \
        { F2 u = __builtin_bit_cast(F2, ACC[5]); a5 = u.x + u.y; }            \
        { F2 u = __builtin_bit_cast(F2, ACC[6]); a6 = u.x + u.y; }            \
        { F2 u = __builtin_bit_cast(F2, ACC[7]); a7 = u.x + u.y; }            \
        float c0 = a0 + dpp_get<0xB1>(a1);                                    \
        float c2 = a4 + dpp_get<0xB1>(a5);                                    \
        float c1 = a2 + dpp_get<0xB1>(a3);                                    \
        float c3 = a6 + dpp_get<0xB1>(a7);                                    \
        float d1 = c0 + dpp_get<0x4E>(c1);                                    \
        float d2 = c2 + dpp_get<0x4E>(c3);                                    \
        d1 += dpp_get<0x124>(d1);                                             \
        d2 += dpp_get<0x124>(d2);                                             \
        d1 += dpp_get<0x128>(d1);                                             \
        d2 += dpp_get<0x128>(d2);                                             \
        HV1 = tanh_pre(d1, bias_k);                                           \
        HV2 = tanh_pre(d2, bias_k2);                                          \
    }

// tick1 (bank P): finish B step i-1 (reduce/tanh/write) under A's ds_read
// latency; then FMA A step i. One barrier.
#define TICK1(P)                                                              \
    {                                                                         \
        const double2* hbd = (const double2*)&hbuf[0][P][0];                  \
        const double2 H0 = hbd[s];                                            \
        const double2 H1 = hbd[16 + s];                                       \
        REDUCE8(accB, hvB1, hvB2);                                            \
        if (wr) {                                                             \
            hbuf[1][P][jj]     = hvB1;                                        \
            hbuf[1][P][jj + 4] = hvB2;                                        \
            outpB[0] = hvB1; outpB[4] = hvB2;                                 \
        }                                                                     \
        outpB += BATCH * HID;                                                 \
        FMA8(accA, cxA, H0, H1);                                              \
        asm volatile("s_waitcnt lgkmcnt(0)" ::: "memory");                    \
        asm volatile("s_barrier" ::: "memory");                               \
    }

// tick2 (read bank P, write bank Q=P^1): finish A step i under B's ds_read
// latency; then FMA B step i. One barrier.
#define TICK2(P, Q)                                                           \
    {                                                                         \
        const double2* hbd = (const double2*)&hbuf[1][P][0];                  \
        const double2 H0 = hbd[s];                                            \
        const double2 H1 = hbd[16 + s];                                       \
        REDUCE8(accA, hvA1, hvA2);                                            \
        if (wr) {                                                             \
            hbuf[0][Q][jj]     = hvA1;                                        \
            hbuf[0][Q][jj + 4] = hvA2;                                        \
            outpA[0] = hvA1; outpA[4] = hvA2;                                 \
        }                                                                     \
        outpA += BATCH * HID;                                                 \
        FMA8(accB, cxB, H0, H1);                                              \
        asm volatile("s_waitcnt lgkmcnt(0)" ::: "memory");                    \
        asm volatile("s_barrier" ::: "memory");                               \
    }

    // ---- peeled iteration 0: no B-reduce yet (no step -1)
    XLOAD(0);
    {
        const double2* hbd = (const double2*)&hbuf[0][0][0];   // zeros
        const double2 H0 = hbd[s];
        const double2 H1 = hbd[16 + s];
        FMA8(accA, cxA, H0, H1);
        asm volatile("s_waitcnt lgkmcnt(0)" ::: "memory");
        asm volatile("s_barrier" ::: "memory");
    }
    TICK2(0, 1);   // reduce A step 0 -> hbufA[1]; FMA B step 0 (h=0, bank0)
    XROT();

    // ---- main: iterations 1..2046 in pairs (odd: banks 1, even: banks 0)
    for (int m = 0; m < 1023; ++m) {
        PIN_WEIGHTS();
        XLOAD(2 * m + 1);
        TICK1(1);
        TICK2(1, 0);
        XROT();
        XLOAD(2 * m + 2);
        TICK1(0);
        TICK2(0, 1);
        XROT();
    }

    // ---- peeled iteration 2047 (banks 1)
    XLOAD(2047);
    TICK1(1);
    TICK2(1, 0);

    // ---- epilogue: B step 2047 + final states (1,B,H)
    REDUCE8(accB, hvB1, hvB2);
    if (wr) {
        outpB[0] = hvB1; outpB[4] = hvB2;
        float* fs = out + (size_t)SEQ * BATCH * HID;
        fs[(size_t)b0 * HID + jj]           = hvA1;
        fs[(size_t)b0 * HID + jj + 4]       = hvA2;
        fs[(size_t)(b0 + 1) * HID + jj]     = hvB1;
        fs[(size_t)(b0 + 1) * HID + jj + 4] = hvB2;
    }
}

extern "C" void kernel_launch(void* const* d_in, const int* in_sizes, int n_in,
                              void* d_out, int out_size, void* d_ws, size_t ws_size,
                              hipStream_t stream) {
    const float* x  = (const float*)d_in[0];
    const float* Wx = (const float*)d_in[1];
    const float* bx = (const float*)d_in[2];
    const float* Wh = (const float*)d_in[3];
    const float* bh = (const float*)d_in[4];
    float* out = (float*)d_out;
    (void)in_sizes; (void)n_in; (void)d_ws; (void)ws_size; (void)out_size;
    rnn_fused<<<dim3(BATCH / 2), dim3(256), 0, stream>>>(x, Wx, bx, Wh, bh, out);
}

// Round 6
// 620.790 us; speedup vs baseline: 2.2762x; 2.2762x over previous
//
#include <hip/hip_runtime.h>

#define SEQ   2048
#define BATCH 256
#define INDIM 64
#define HID   128

struct F2 { float x, y; };

// Permuted value via DPP. CTRL: 0xB1 quad_perm xor1, 0x4E quad_perm xor2,
// 0x124 row_ror:4, 0x128 row_ror:8.
template <int CTRL>
__device__ __forceinline__ float dpp_get(float v) {
    int t = __builtin_amdgcn_update_dpp(0, __builtin_bit_cast(int, v),
                                        CTRL, 0xF, 0xF, true);
    return __builtin_bit_cast(float, t);
}

// Packed fp32 math (VOP3P): 2 FMAs/lane/inst.
#define PK_MUL(d, a, b) asm("v_pk_mul_f32 %0, %1, %2"     : "=v"(d) : "v"(a), "v"(b))
#define PK_FMA(d, a, b) asm("v_pk_fma_f32 %0, %1, %2, %0" : "+v"(d) : "v"(a), "v"(b))

// tanh(d + bias) with bias pre-folded: m = d*K + bias*K, K = -2/ln2;
// e = 2^m = e^{-2(d+bias)}; tanh = (1-e)/(1+e).
#define TANH_K (-2.885390081777927f)
__device__ __forceinline__ float tanh_pre(float d, float bias_k) {
    float m = __builtin_fmaf(d, TANH_K, bias_k);
    float e = __builtin_amdgcn_exp2f(m);
    return (1.0f - e) * __builtin_amdgcn_rcpf(1.0f + e);
}

// R16 = R15 (x-partial ping-pong) SCALARIZED: step t computes step t+1's
// x-projection partials inside step t's post-barrier ds_read shadow, so the
// post-waitcnt dependent block shrinks from 24 to 16 pk-insts per wave.
// The two accumulator banks are eight NAMED doubles threaded through the
// step macro by name — no aggregate persists across a barrier (R14 showed
// the compiler demotes pressured aggregates to LDS; R15's array-based
// version of this kernel crashed at runtime). Everything else is the
// proven 604us baseline byte-for-byte.
__global__ __launch_bounds__(512)
__attribute__((amdgpu_waves_per_eu(2, 2)))   // proven allocation regime
void rnn_fused(
    const float* __restrict__ x,    // (S,B,IN)
    const float* __restrict__ Wx,   // (H,IN)
    const float* __restrict__ bx,   // (H)
    const float* __restrict__ Wh,   // (H,H)
    const float* __restrict__ bh,   // (H)
    float* __restrict__ out)        // (S,B,H) then (1,B,H)
{
    const int b   = blockIdx.x;
    const int tid = threadIdx.x;     // 0..511 (8 waves, 2/SIMD)
    const int l   = tid & 63;
    const int w   = tid >> 6;
    const int s   = l & 15;          // k-slice: h[4s..4s+3], h[64+4s..+3], x[4s..+3]
    const int j0  = w * 16 + (l >> 4) * 4;   // group base: outputs j0..j0+3

    __shared__ __align__(16) float hbuf[2][HID];   // only h lives in LDS

    // ---- weights as packed float-pairs, SLOT-PERMUTED: accumulator slot o
    // holds output j0 + (o ^ (l&3)) -> cndmask-free butterfly.
    const double* WhD = (const double*)Wh;   // 64 doubles per row
    const double* WxD = (const double*)Wx;   // 32 doubles per row
    double wA[4], wB[4], wC[4], wD[4], wX[4], wY[4];
#pragma unroll
    for (int o = 0; o < 4; ++o) {
        const int row = j0 + (o ^ (l & 3));        // slot-permuted output row
        const int r   = row * 64 + 2 * s;
        wA[o] = WhD[r];      wB[o] = WhD[r + 1];
        wC[o] = WhD[r + 32]; wD[o] = WhD[r + 33];
        const int rx  = row * 32 + 2 * s;
        wX[o] = WxD[rx];     wY[o] = WxD[rx + 1];
    }
    const int jj = j0 + (l & 3);          // output this lane holds after reduce
    float bias_k = (bx[jj] + bh[jj]) * TANH_K;   // pre-folded into exp arg

    if (tid < 256) hbuf[tid >> 7][tid & 127] = 0.0f;
    __syncthreads();

    // x in registers: per-thread double2 (=float4) slice, 4-step banks,
    // double-buffered. Compiler-placed vmcnt waits land near bank rotation.
    const double2* xb2 = (const double2*)(x + (size_t)b * INDIM + 4 * s);
    const size_t   S2  = (size_t)BATCH * INDIM / 4;   // double2 per timestep
    double2 xa0, xa1, xa2, xa3, xn0, xn1, xn2, xn3;
    xa0 = xb2[0]; xa1 = xb2[S2]; xa2 = xb2[2 * S2]; xa3 = xb2[3 * S2];

    float* outp = out + (size_t)b * HID + jj;  // running pointer
    const bool wr = (s < 4);                   // 16 lanes/wave write
    float hv = 0.0f;

    // Ping-pong accumulator banks as NAMED scalars. Bank E pre-seeded with
    // step 0's x-partials; each step seeds the other bank in its shadow.
    double aE0, aE1, aE2, aE3, aO0, aO1, aO2, aO3;
    PK_MUL(aE0, xa0.x, wX[0]); PK_MUL(aE1, xa0.x, wX[1]);
    PK_MUL(aE2, xa0.x, wX[2]); PK_MUL(aE3, xa0.x, wX[3]);
    PK_FMA(aE0, xa0.y, wY[0]); PK_FMA(aE1, xa0.y, wY[1]);
    PK_FMA(aE2, xa0.y, wY[2]); PK_FMA(aE3, xa0.y, wY[3]);

// One timestep. C0..C3 = this step's acc (x-terms already in),
// N0..N3 = next step's acc (seeded with XN here, in the ds_read shadow).
#define STEP(Q, C0, C1, C2, C3, N0, N1, N2, N3, XN)                           \
    {                                                                         \
        const double2* hbd = (const double2*)&hbuf[(Q) & 1][0];               \
        const double2 H0 = hbd[s];            /* ds_read_b128 */              \
        const double2 H1 = hbd[16 + s];       /* ds_read_b128 */              \
        const double2 Xn = XN;                                                \
        /* shadow work: next step's x-partials (independent of H) */          \
        PK_MUL(N0, Xn.x, wX[0]); PK_MUL(N1, Xn.x, wX[1]);                     \
        PK_MUL(N2, Xn.x, wX[2]); PK_MUL(N3, Xn.x, wX[3]);                     \
        PK_FMA(N0, Xn.y, wY[0]); PK_FMA(N1, Xn.y, wY[1]);                     \
        PK_FMA(N2, Xn.y, wY[2]); PK_FMA(N3, Xn.y, wY[3]);                     \
        /* post-wait block: pure H-FMAs into the pre-seeded acc */            \
        PK_FMA(C0, H0.x, wA[0]); PK_FMA(C1, H0.x, wA[1]);                     \
        PK_FMA(C2, H0.x, wA[2]); PK_FMA(C3, H0.x, wA[3]);                     \
        PK_FMA(C0, H0.y, wB[0]); PK_FMA(C1, H0.y, wB[1]);                     \
        PK_FMA(C2, H0.y, wB[2]); PK_FMA(C3, H0.y, wB[3]);                     \
        PK_FMA(C0, H1.x, wC[0]); PK_FMA(C1, H1.x, wC[1]);                     \
        PK_FMA(C2, H1.x, wC[2]); PK_FMA(C3, H1.x, wC[3]);                     \
        PK_FMA(C0, H1.y, wD[0]); PK_FMA(C1, H1.y, wD[1]);                     \
        PK_FMA(C2, H1.y, wD[2]); PK_FMA(C3, H1.y, wD[3]);                     \
        float a0, a1, a2, a3;                                                 \
        { F2 u = __builtin_bit_cast(F2, C0); a0 = u.x + u.y; }                \
        { F2 u = __builtin_bit_cast(F2, C1); a1 = u.x + u.y; }                \
        { F2 u = __builtin_bit_cast(F2, C2); a2 = u.x + u.y; }                \
        { F2 u = __builtin_bit_cast(F2, C3); a3 = u.x + u.y; }                \
        float c0 = a0 + dpp_get<0xB1>(a1);                                    \
        float c1 = a2 + dpp_get<0xB1>(a3);                                    \
        float d  = c0 + dpp_get<0x4E>(c1);                                    \
        d += dpp_get<0x124>(d);                                               \
        d += dpp_get<0x128>(d);                                               \
        hv = tanh_pre(d, bias_k);                                             \
        if (wr) {                            /* 16 lanes/wave */              \
            hbuf[((Q) + 1) & 1][jj] = hv;                                     \
            *outp = hv;                      /* store never blocks */         \
        }                                                                     \
        outp += BATCH * HID;                                                  \
        asm volatile("s_waitcnt lgkmcnt(0)" ::: "memory");                    \
        asm volatile("s_barrier" ::: "memory");                               \
    }

    for (int tb = 0; tb < SEQ; tb += 4) {
        // In-loop pin (once per 4 steps): loop-carried "+v" keeps weights
        // VGPR-resident — no AGPR parking, no remat.
        asm volatile("" : "+v"(wA[0]), "+v"(wA[1]), "+v"(wA[2]), "+v"(wA[3]));
        asm volatile("" : "+v"(wB[0]), "+v"(wB[1]), "+v"(wB[2]), "+v"(wB[3]));
        asm volatile("" : "+v"(wC[0]), "+v"(wC[1]), "+v"(wC[2]), "+v"(wC[3]));
        asm volatile("" : "+v"(wD[0]), "+v"(wD[1]), "+v"(wD[2]), "+v"(wD[3]));
        asm volatile("" : "+v"(wX[0]), "+v"(wX[1]), "+v"(wX[2]), "+v"(wX[3]));
        asm volatile("" : "+v"(wY[0]), "+v"(wY[1]), "+v"(wY[2]), "+v"(wY[3]));
        asm volatile("" : "+v"(bias_k));

        // issue next bank (steps tb+4..tb+7, clamped at the tail)
        {
            int t0 = tb + 4, t1 = tb + 5, t2 = tb + 6, t3 = tb + 7;
            if (t0 > SEQ - 1) t0 = SEQ - 1;
            if (t1 > SEQ - 1) t1 = SEQ - 1;
            if (t2 > SEQ - 1) t2 = SEQ - 1;
            if (t3 > SEQ - 1) t3 = SEQ - 1;
            xn0 = xb2[(size_t)t0 * S2];
            xn1 = xb2[(size_t)t1 * S2];
            xn2 = xb2[(size_t)t2 * S2];
            xn3 = xb2[(size_t)t3 * S2];
        }

        // steps tb..tb+3; step q's shadow seeds step q+1's x-partials.
        STEP(0, aE0, aE1, aE2, aE3, aO0, aO1, aO2, aO3, xa1);
        STEP(1, aO0, aO1, aO2, aO3, aE0, aE1, aE2, aE3, xa2);
        STEP(2, aE0, aE1, aE2, aE3, aO0, aO1, aO2, aO3, xa3);
        STEP(3, aO0, aO1, aO2, aO3, aE0, aE1, aE2, aE3, xn0);

        // rotate banks (remaining vmcnt waits land here)
        xa0 = xn0; xa1 = xn1; xa2 = xn2; xa3 = xn3;
    }

    // final state (1,B,H): peeled from the loop
    if (wr)
        out[(size_t)SEQ * BATCH * HID + (size_t)b * HID + jj] = hv;
}

extern "C" void kernel_launch(void* const* d_in, const int* in_sizes, int n_in,
                              void* d_out, int out_size, void* d_ws, size_t ws_size,
                              hipStream_t stream) {
    const float* x  = (const float*)d_in[0];
    const float* Wx = (const float*)d_in[1];
    const float* bx = (const float*)d_in[2];
    const float* Wh = (const float*)d_in[3];
    const float* bh = (const float*)d_in[4];
    float* out = (float*)d_out;
    (void)in_sizes; (void)n_in; (void)d_ws; (void)ws_size; (void)out_size;
    rnn_fused<<<dim3(BATCH), dim3(512), 0, stream>>>(x, Wx, bx, Wh, bh, out);
}

// Round 7
// 611.512 us; speedup vs baseline: 2.3108x; 1.0152x over previous
//
#include <hip/hip_runtime.h>

#define SEQ   2048
#define BATCH 256
#define INDIM 64
#define HID   128

struct F2 { float x, y; };

// Permuted value via DPP. CTRL: 0xB1 quad_perm xor1, 0x4E quad_perm xor2,
// 0x124 row_ror:4, 0x128 row_ror:8.
template <int CTRL>
__device__ __forceinline__ float dpp_get(float v) {
    int t = __builtin_amdgcn_update_dpp(0, __builtin_bit_cast(int, v),
                                        CTRL, 0xF, 0xF, true);
    return __builtin_bit_cast(float, t);
}

// Packed fp32 math (VOP3P): 2 FMAs/lane/inst.
#define PK_MUL(d, a, b) asm("v_pk_mul_f32 %0, %1, %2"     : "=v"(d) : "v"(a), "v"(b))
#define PK_FMA(d, a, b) asm("v_pk_fma_f32 %0, %1, %2, %0" : "+v"(d) : "v"(a), "v"(b))

// tanh(d + bias) with bias pre-folded: m = d*K + bias*K, K = -2/ln2;
// e = 2^m = e^{-2(d+bias)}; tanh = (1-e)/(1+e). No abs/copysign needed:
// |d+bias| small -> e finite both directions. Chain: fma, exp2, add/sub, rcp, mul.
#define TANH_K (-2.885390081777927f)
__device__ __forceinline__ float tanh_pre(float d, float bias_k) {
    float m = __builtin_fmaf(d, TANH_K, bias_k);
    float e = __builtin_amdgcn_exp2f(m);
    return (1.0f - e) * __builtin_amdgcn_rcpf(1.0f + e);
}

// FINAL (restored R0, session best 604us). Structural floor for this op:
// 2048 inherently-sequential steps x ~708cy = issue (~200cy/SIMD) + serial
// exchange chain (ds_write vis + 8-wave barrier + ~120cy ds_read latency +
// 4-level DPP reduce + tanh). Experiments R11-R16 (journal): dual-chain
// TLP/ILP/phase-shifted all defeated by allocator parking/demotion at
// +50 VGPR live-set growth (52-VGPR AGPR-parking, 88-cap parking, 18KB LDS
// demotion); 4-wave variant loses serial-chain hiding (633us); x-partial
// ping-pong neutral (shadow already full, 620us). HBM 5%, conflicts 0,
// true VALU ~26% -> latency-structure-bound, not resource-bound.
__global__ __launch_bounds__(512)
__attribute__((amdgpu_waves_per_eu(2, 2)))   // R5/R8/R10-proven: 2 waves/SIMD
void rnn_fused(
    const float* __restrict__ x,    // (S,B,IN)
    const float* __restrict__ Wx,   // (H,IN)
    const float* __restrict__ bx,   // (H)
    const float* __restrict__ Wh,   // (H,H)
    const float* __restrict__ bh,   // (H)
    float* __restrict__ out)        // (S,B,H) then (1,B,H)
{
    const int b   = blockIdx.x;
    const int tid = threadIdx.x;     // 0..511 (8 waves, 2/SIMD)
    const int l   = tid & 63;
    const int w   = tid >> 6;
    const int s   = l & 15;          // k-slice: h[4s..4s+3], h[64+4s..+3], x[4s..+3]
    const int j0  = w * 16 + (l >> 4) * 4;   // group base: outputs j0..j0+3

    __shared__ __align__(16) float hbuf[2][HID];   // only h lives in LDS

    // ---- weights as packed float-pairs, SLOT-PERMUTED: accumulator slot o
    // holds output j0 + (o ^ (l&3)). This bakes the output->lane routing of
    // the transposed reduce into the weight assignment, so the butterfly
    // needs NO cndmask selects (pure fused dpp-adds on the critical path).
    const double* WhD = (const double*)Wh;   // 64 doubles per row
    const double* WxD = (const double*)Wx;   // 32 doubles per row
    double wA[4], wB[4], wC[4], wD[4], wX[4], wY[4];
#pragma unroll
    for (int o = 0; o < 4; ++o) {
        const int row = j0 + (o ^ (l & 3));        // slot-permuted output row
        const int r   = row * 64 + 2 * s;
        wA[o] = WhD[r];      wB[o] = WhD[r + 1];
        wC[o] = WhD[r + 32]; wD[o] = WhD[r + 33];
        const int rx  = row * 32 + 2 * s;
        wX[o] = WxD[rx];     wY[o] = WxD[rx + 1];
    }
    const int jj = j0 + (l & 3);          // output this lane holds after reduce
    float bias_k = (bx[jj] + bh[jj]) * TANH_K;   // pre-folded into exp arg

    if (tid < 256) hbuf[tid >> 7][tid & 127] = 0.0f;
    __syncthreads();

    // x in registers: per-thread double2 (=float4) slice, 4-step banks,
    // double-buffered. Only VMEM waits are compiler-placed before bank
    // rotation, ~4 steps after issue -> retire instantly (R7/R8 win).
    const double2* xb2 = (const double2*)(x + (size_t)b * INDIM + 4 * s);
    const size_t   S2  = (size_t)BATCH * INDIM / 4;   // double2 per timestep
    double2 xa[4], xn[4];
#pragma unroll
    for (int i = 0; i < 4; ++i) xa[i] = xb2[(size_t)i * S2];

    float* outp = out + (size_t)b * HID + jj;  // running pointer: no per-step
    const bool wr = (s < 4);                   // 64-bit address arithmetic
    float hv = 0.0f;

    for (int tb = 0; tb < SEQ; tb += 4) {
        // In-loop pin (once per 4 steps): loop-carried "+v" keeps weights
        // VGPR-resident — no AGPR parking, no remat (round-3/5 lesson).
        asm volatile("" : "+v"(wA[0]), "+v"(wA[1]), "+v"(wA[2]), "+v"(wA[3]));
        asm volatile("" : "+v"(wB[0]), "+v"(wB[1]), "+v"(wB[2]), "+v"(wB[3]));
        asm volatile("" : "+v"(wC[0]), "+v"(wC[1]), "+v"(wC[2]), "+v"(wC[3]));
        asm volatile("" : "+v"(wD[0]), "+v"(wD[1]), "+v"(wD[2]), "+v"(wD[3]));
        asm volatile("" : "+v"(wX[0]), "+v"(wX[1]), "+v"(wX[2]), "+v"(wX[3]));
        asm volatile("" : "+v"(wY[0]), "+v"(wY[1]), "+v"(wY[2]), "+v"(wY[3]));
        asm volatile("" : "+v"(bias_k));

        // issue next bank (steps tb+4..tb+7, clamped at the tail)
#pragma unroll
        for (int i = 0; i < 4; ++i) {
            int tp = tb + 4 + i; if (tp > SEQ - 1) tp = SEQ - 1;
            xn[i] = xb2[(size_t)tp * S2];
        }

#pragma unroll
        for (int q = 0; q < 4; ++q) {
            const double2* hbd = (const double2*)&hbuf[q & 1][0];

            // 2 ds_read_b128: granules s and 16+s, 4-way g-broadcast — conflict-free
            const double2 H0 = hbd[s];
            const double2 H1 = hbd[16 + s];
            const double2 X  = xa[q];

            double acc0, acc1, acc2, acc3;
            // x first: independent of h -> schedules into ds_read shadow
            PK_MUL(acc0, X.x, wX[0]); PK_MUL(acc1, X.x, wX[1]);
            PK_MUL(acc2, X.x, wX[2]); PK_MUL(acc3, X.x, wX[3]);
            PK_FMA(acc0, X.y, wY[0]); PK_FMA(acc1, X.y, wY[1]);
            PK_FMA(acc2, X.y, wY[2]); PK_FMA(acc3, X.y, wY[3]);
            PK_FMA(acc0, H0.x, wA[0]); PK_FMA(acc1, H0.x, wA[1]);
            PK_FMA(acc2, H0.x, wA[2]); PK_FMA(acc3, H0.x, wA[3]);
            PK_FMA(acc0, H0.y, wB[0]); PK_FMA(acc1, H0.y, wB[1]);
            PK_FMA(acc2, H0.y, wB[2]); PK_FMA(acc3, H0.y, wB[3]);
            PK_FMA(acc0, H1.x, wC[0]); PK_FMA(acc1, H1.x, wC[1]);
            PK_FMA(acc2, H1.x, wC[2]); PK_FMA(acc3, H1.x, wC[3]);
            PK_FMA(acc0, H1.y, wD[0]); PK_FMA(acc1, H1.y, wD[1]);
            PK_FMA(acc2, H1.y, wD[2]); PK_FMA(acc3, H1.y, wD[3]);

            float a0, a1, a2, a3;
            { F2 u = __builtin_bit_cast(F2, acc0); a0 = u.x + u.y; }
            { F2 u = __builtin_bit_cast(F2, acc1); a1 = u.x + u.y; }
            { F2 u = __builtin_bit_cast(F2, acc2); a2 = u.x + u.y; }
            { F2 u = __builtin_bit_cast(F2, acc3); a3 = u.x + u.y; }

            // cndmask-free butterfly (slot permutation did the routing):
            // c0/c1 pair slice s with s^1; d pairs with s^2; ror4+ror8
            // all-reduce the remaining slice bits. Lane ends with out jj.
            float c0 = a0 + dpp_get<0xB1>(a1);
            float c1 = a2 + dpp_get<0xB1>(a3);
            float d  = c0 + dpp_get<0x4E>(c1);
            d += dpp_get<0x124>(d);
            d += dpp_get<0x128>(d);

            hv = tanh_pre(d, bias_k);      // bias folded into exp arg

            if (wr) {                      // 16 lanes/wave, contiguous dwords
                hbuf[(q + 1) & 1][jj] = hv;
                *outp = hv;                // store never blocks (no vmcnt waits)
            }
            outp += BATCH * HID;

            // h-exchange sync only: lgkmcnt(0) -> ds_write visible; raw
            // s_barrier is opaque to SIInsertWaitcnts (no hidden vmcnt(0)).
            asm volatile("s_waitcnt lgkmcnt(0)" ::: "memory");
            asm volatile("s_barrier" ::: "memory");
        }

        // rotate banks (vmcnt wait lands here, ~4 steps after issue)
#pragma unroll
        for (int i = 0; i < 4; ++i) xa[i] = xn[i];
    }

    // final state (1,B,H): peeled from the loop
    if (wr)
        out[(size_t)SEQ * BATCH * HID + (size_t)b * HID + jj] = hv;
}

extern "C" void kernel_launch(void* const* d_in, const int* in_sizes, int n_in,
                              void* d_out, int out_size, void* d_ws, size_t ws_size,
                              hipStream_t stream) {
    const float* x  = (const float*)d_in[0];
    const float* Wx = (const float*)d_in[1];
    const float* bx = (const float*)d_in[2];
    const float* Wh = (const float*)d_in[3];
    const float* bh = (const float*)d_in[4];
    float* out = (float*)d_out;
    (void)in_sizes; (void)n_in; (void)d_ws; (void)ws_size; (void)out_size;
    rnn_fused<<<dim3(BATCH), dim3(512), 0, stream>>>(x, Wx, bx, Wh, bh, out);
}